// Round 1
// baseline (394.526 us; speedup 1.0000x reference)
//
#include <hip/hip_runtime.h>
#include <stdint.h>

// LePE windowed attention, MI355X gfx950. Round 5:
//  - p_lds transpose replaced by in-register quad exchange (permlane32/16_swap):
//    LDS 52224 -> 38656 B => 4 blocks/CU (launch_bounds 256,4), no lgkmcnt(0) drains in PV.
//  - KSTR 32 -> 40 u16 (80B row): K ds_read_b128 8-way conflict -> ~2-way; staging writes 32->8-way.
//  - Q prefetched for all 4 iters before staging (global latency hidden under staging).
//  - LePE hoisted between S^T MFMA issue and softmax (fills MFMA drain); setprio around MFMA.
// Inputs fp32: qkv (3,2,32768,256); conv_w (256,1,3,3); conv_b (256). Output fp32 (2,32768,256).
// Windows: H_SP=32, W_SP=8 -> 256 windows, S=256, heads=8, hd=32. Block per (window,head): grid 2048.

typedef short bf16x8 __attribute__((ext_vector_type(8)));
typedef uint16_t u16x4 __attribute__((ext_vector_type(4)));
typedef float f32x4 __attribute__((ext_vector_type(4)));
typedef uint32_t u32x4 __attribute__((ext_vector_type(4)));

#define KSTR 40    // K rows: 256 x 40 u16 (64B data + 16B pad -> bank-phase rotation 4*(5*row%8))
#define VSTR 264   // Vt rows: 32 x 264 (pad 8: bank rotation + b128 alignment)

__device__ __forceinline__ float bf2f_lo(uint32_t u) {
    union { uint32_t i; float f; } x; x.i = u << 16; return x.f;
}
__device__ __forceinline__ float bf2f_hi(uint32_t u) {
    union { uint32_t i; float f; } x; x.i = u & 0xffff0000u; return x.f;
}
__device__ __forceinline__ uint16_t f2bf(float f) {
    union { float f; uint32_t i; } x; x.f = f;
    return (uint16_t)((x.i + 0x7fffu + ((x.i >> 16) & 1u)) >> 16);
}
__device__ __forceinline__ uint32_t fbits(float f) {
    union { float f; uint32_t i; } x; x.f = f; return x.i;
}

__global__ __launch_bounds__(256, 4)
void lepe_attn(const float* __restrict__ qkv,
               const float* __restrict__ conv_w,
               const float* __restrict__ conv_b,
               float* __restrict__ out)
{
    __shared__ uint16_t k_lds[256 * KSTR];       // 20480 B
    __shared__ uint16_t vt_lds[32 * VSTR];       // 16896 B
    __shared__ float w_lds[288];                 //  1152 B
    __shared__ float b_lds[32];                  //   128 B  => total 38656 B

    const int tid  = threadIdx.x;
    const int lane = tid & 63;
    const int wave = tid >> 6;
    const int l15  = lane & 15;
    const int quad = lane >> 4;

    const int blk  = blockIdx.x;
    const int head = blk & 7;
    const int wid  = blk >> 3;
    const int b    = wid >> 7;
    const int rem  = wid & 127;
    const int dpt  = rem >> 2;
    const int nw   = rem & 3;

    const long base_l = (long)dpt * 1024 + nw * 8;
    const int  hc     = head * 32;

    const float c1 = 0.17677669529663687f * 1.4426950408889634f; // SCALE * log2(e)

    // ---- Q prefetch: all 4 iterations, issued BEFORE staging loads ----
    float4 qpre[8];
    #pragma unroll
    for (int it = 0; it < 4; ++it) {
        const int  sq = (wave * 4 + it) * 16 + l15;
        const long ql = base_l + (sq >> 3) * 32 + (sq & 7);
        const float* qp = qkv + (((long)b * 32768 + ql) * 256 + hc + quad * 8);
        qpre[it * 2]     = ((const float4*)qp)[0];
        qpre[it * 2 + 1] = ((const float4*)qp)[1];
    }

    // ---- stage K [t][hd] bf16 (pad-40), V^T [hd][t] bf16, LePE weights fp32 ----
    {
        const int  s = tid;
        const long l = base_l + (s >> 3) * 32 + (s & 7);
        const float* kp = qkv + (((long)(2 + b) * 32768 + l) * 256 + hc);
        const float* vp = qkv + (((long)(4 + b) * 32768 + l) * 256 + hc);
        #pragma unroll
        for (int j = 0; j < 8; ++j) {
            float4 kv = ((const float4*)kp)[j];
            u16x4 kb = { f2bf(kv.x), f2bf(kv.y), f2bf(kv.z), f2bf(kv.w) };
            *(u16x4*)&k_lds[s * KSTR + j * 4] = kb;
            float4 vv = ((const float4*)vp)[j];
            vt_lds[(j * 4 + 0) * VSTR + s] = f2bf(vv.x);
            vt_lds[(j * 4 + 1) * VSTR + s] = f2bf(vv.y);
            vt_lds[(j * 4 + 2) * VSTR + s] = f2bf(vv.z);
            vt_lds[(j * 4 + 3) * VSTR + s] = f2bf(vv.w);
        }
        for (int i = tid; i < 288; i += 256) w_lds[i] = conv_w[head * 288 + i];
        if (tid < 32) b_lds[tid] = conv_b[hc + tid];
    }

    // convert Q to MFMA B-fragments while staging stores drain (pre-scaled by SCALE*log2e)
    bf16x8 qfa[4];
    #pragma unroll
    for (int it = 0; it < 4; ++it) {
        float4 q0 = qpre[it * 2], q1 = qpre[it * 2 + 1];
        bf16x8 f;
        f[0] = (short)f2bf(q0.x * c1); f[1] = (short)f2bf(q0.y * c1);
        f[2] = (short)f2bf(q0.z * c1); f[3] = (short)f2bf(q0.w * c1);
        f[4] = (short)f2bf(q1.x * c1); f[5] = (short)f2bf(q1.y * c1);
        f[6] = (short)f2bf(q1.z * c1); f[7] = (short)f2bf(q1.w * c1);
        qfa[it] = f;
    }
    __syncthreads();

    // hoist this lane's LePE weights (channels l15 and 16+l15)
    float wgt[18], bia[2];
    #pragma unroll
    for (int n = 0; n < 2; ++n) {
        #pragma unroll
        for (int i = 0; i < 9; ++i) wgt[n * 9 + i] = w_lds[(n * 16 + l15) * 9 + i];
        bia[n] = b_lds[n * 16 + l15];
    }

    const f32x4 zero4 = {0.f, 0.f, 0.f, 0.f};

    #pragma unroll
    for (int it = 0; it < 4; ++it) {
        const int rt = wave * 4 + it;

        // ---- S^T = K Q^T: lane holds S^T[key=16t+quad*4+r][query=rt*16+l15] ----
        f32x4 accS[16];
        __builtin_amdgcn_s_setprio(1);
        #pragma unroll
        for (int t = 0; t < 16; ++t) {
            bf16x8 afrag = *(const bf16x8*)&k_lds[(t * 16 + l15) * KSTR + quad * 8];
            accS[t] = __builtin_amdgcn_mfma_f32_16x16x32_bf16(afrag, qfa[it], zero4, 0, 0, 0);
        }
        __builtin_amdgcn_s_setprio(0);

        // ---- LePE (independent of accS): fills S^T MFMA drain latency ----
        const int hrow = rt * 2 + (quad >> 1);
        const int wsel = quad & 1;
        float lep[2][4];
        #pragma unroll
        for (int n = 0; n < 2; ++n) {
            const int d = n * 16 + l15;
            float lep0 = bia[n], lep1 = bia[n], lep2 = bia[n], lep3 = bia[n];
            #pragma unroll
            for (int dy = 0; dy < 3; ++dy) {
                const int hh = hrow + dy - 1;
                float e0 = 0.f, e1 = 0.f, e2 = 0.f, e3 = 0.f, e4 = 0.f, e5 = 0.f;
                if (hh >= 0 && hh < 32) {
                    uint4 rv = *(const uint4*)&vt_lds[d * VSTR + hh * 8];
                    float c0 = bf2f_lo(rv.x), c1v = bf2f_hi(rv.x);
                    float c2 = bf2f_lo(rv.y), c3 = bf2f_hi(rv.y);
                    float c4 = bf2f_lo(rv.z), c5 = bf2f_hi(rv.z);
                    float c6 = bf2f_lo(rv.w), c7 = bf2f_hi(rv.w);
                    e0 = wsel ? c3 : 0.f;  e1 = wsel ? c4 : c0;
                    e2 = wsel ? c5 : c1v;  e3 = wsel ? c6 : c2;
                    e4 = wsel ? c7 : c3;   e5 = wsel ? 0.f : c4;
                }
                const float w0 = wgt[n * 9 + dy * 3 + 0];
                const float w1 = wgt[n * 9 + dy * 3 + 1];
                const float w2 = wgt[n * 9 + dy * 3 + 2];
                lep0 = fmaf(w0, e0, fmaf(w1, e1, fmaf(w2, e2, lep0)));
                lep1 = fmaf(w0, e1, fmaf(w1, e2, fmaf(w2, e3, lep1)));
                lep2 = fmaf(w0, e2, fmaf(w1, e3, fmaf(w2, e4, lep2)));
                lep3 = fmaf(w0, e3, fmaf(w1, e4, fmaf(w2, e5, lep3)));
            }
            lep[n][0] = lep0; lep[n][1] = lep1; lep[n][2] = lep2; lep[n][3] = lep3;
        }

        // ---- softmax (max-free) + pack P to bf16 pairs; accS[t] dies into pkl/pkh[t] ----
        uint32_t pkl[16], pkh[16];
        float ssum = 0.f;
        #pragma unroll
        for (int t = 0; t < 16; ++t) {
            float p0 = exp2f(accS[t][0]);
            float p1 = exp2f(accS[t][1]);
            float p2 = exp2f(accS[t][2]);
            float p3 = exp2f(accS[t][3]);
            ssum += (p0 + p1) + (p2 + p3);
            pkl[t] = ((fbits(p0) + 0x8000u) >> 16) | ((fbits(p1) + 0x8000u) & 0xffff0000u);
            pkh[t] = ((fbits(p2) + 0x8000u) >> 16) | ((fbits(p3) + 0x8000u) & 0xffff0000u);
        }
        ssum += __shfl_xor(ssum, 16);
        ssum += __shfl_xor(ssum, 32);
        const float linv = __builtin_amdgcn_rcpf(ssum);
        // output row r of this lane is query quad*4+r; its sum lives at lane l15'=quad*4+r
        float linv4[4];
        #pragma unroll
        for (int r = 0; r < 4; ++r) linv4[r] = __shfl(linv, quad * 4 + r);

        // ---- PV: in-register quad exchange (replaces p_lds roundtrip) ----
        // Lane (l15,q) holds keys {16t+4q+r}; A-fragment needs keys {32cc+8q+0..7}.
        // permlane32_swap then permlane16_swap on (tile 2cc, tile 2cc+1) pairs yields
        // frag dwords: d0=lo(qs=2(q&1)), d1=hi(qs), d2=lo(qs+1), d3=hi(qs+1).
        f32x4 accO[2] = {zero4, zero4};
        __builtin_amdgcn_s_setprio(1);
        #pragma unroll
        for (int cc = 0; cc < 8; ++cc) {
            uint32_t a0 = pkl[2 * cc], a1 = pkl[2 * cc + 1];
            uint32_t b0 = pkh[2 * cc], b1 = pkh[2 * cc + 1];
            asm("v_permlane32_swap_b32 %0, %1" : "+v"(a0), "+v"(a1));
            asm("v_permlane32_swap_b32 %0, %1" : "+v"(b0), "+v"(b1));
            asm("v_permlane16_swap_b32 %0, %1" : "+v"(a0), "+v"(a1));
            asm("v_permlane16_swap_b32 %0, %1" : "+v"(b0), "+v"(b1));
            u32x4 pv = {a0, b0, a1, b1};
            bf16x8 pa = __builtin_bit_cast(bf16x8, pv);
            const int kb = cc * 32 + quad * 8;
            bf16x8 vb0 = *(const bf16x8*)&vt_lds[l15 * VSTR + kb];
            accO[0] = __builtin_amdgcn_mfma_f32_16x16x32_bf16(pa, vb0, accO[0], 0, 0, 0);
            bf16x8 vb1 = *(const bf16x8*)&vt_lds[(16 + l15) * VSTR + kb];
            accO[1] = __builtin_amdgcn_mfma_f32_16x16x32_bf16(pa, vb1, accO[1], 0, 0, 0);
        }
        __builtin_amdgcn_s_setprio(0);

        // ---- epilogue: normalize, add LePE, store ----
        #pragma unroll
        for (int n = 0; n < 2; ++n) {
            const int d = n * 16 + l15;
            #pragma unroll
            for (int r = 0; r < 4; ++r) {
                const int s  = rt * 16 + quad * 4 + r;
                const int h  = s >> 3, w_ = s & 7;
                const long ol = base_l + h * 32 + w_;
                out[((long)b * 32768 + ol) * 256 + hc + d] = accO[n][r] * linv4[r] + lep[n][r];
            }
        }
    }
}

extern "C" void kernel_launch(void* const* d_in, const int* in_sizes, int n_in,
                              void* d_out, int out_size, void* d_ws, size_t ws_size,
                              hipStream_t stream)
{
    const float* qkv = (const float*)d_in[0];
    const float* cw  = (const float*)d_in[1];
    const float* cb  = (const float*)d_in[2];
    float* o = (float*)d_out;
    lepe_attn<<<2048, 256, 0, stream>>>(qkv, cw, cb, o);
}

// Round 2
// 331.388 us; speedup vs baseline: 1.1905x; 1.1905x over previous
//
#include <hip/hip_runtime.h>
#include <stdint.h>

// LePE windowed attention, MI355X gfx950. Round 6:
//  Round-5 post-mortem: __launch_bounds__(256,4) capped unified VGPR+AGPR at 128/wave;
//  accS[16] (64 AGPR) + reported 64 VGPR hit the cap exactly -> scratch spills
//  (FETCH +111MB, WRITE +90MB of pure spill traffic) -> 142->194us regression.
//  Fix: revert to (256,3) (budget ~170 regs, spill-free). KEEP the round-5 structural wins:
//  - p_lds transpose replaced by in-register quad exchange (permlane32/16_swap):
//    no lgkmcnt(0) drains in PV, LDS 38656 B.
//  - KSTR 40 u16 (80B row): K ds_read_b128 8-way conflict -> ~2-way (bank-phase rotation).
//  - Q prefetched for all 4 iters before staging (global latency hidden under staging).
//  - LePE hoisted between S^T MFMA issue and softmax (fills MFMA drain); setprio around MFMA.
// Inputs fp32: qkv (3,2,32768,256); conv_w (256,1,3,3); conv_b (256). Output fp32 (2,32768,256).
// Windows: H_SP=32, W_SP=8 -> 256 windows, S=256, heads=8, hd=32. Block per (window,head): grid 2048.

typedef short bf16x8 __attribute__((ext_vector_type(8)));
typedef uint16_t u16x4 __attribute__((ext_vector_type(4)));
typedef float f32x4 __attribute__((ext_vector_type(4)));
typedef uint32_t u32x4 __attribute__((ext_vector_type(4)));

#define KSTR 40    // K rows: 256 x 40 u16 (64B data + 16B pad -> bank-phase rotation 4*(5*row%8))
#define VSTR 264   // Vt rows: 32 x 264 (pad 8: bank rotation + b128 alignment)

__device__ __forceinline__ float bf2f_lo(uint32_t u) {
    union { uint32_t i; float f; } x; x.i = u << 16; return x.f;
}
__device__ __forceinline__ float bf2f_hi(uint32_t u) {
    union { uint32_t i; float f; } x; x.i = u & 0xffff0000u; return x.f;
}
__device__ __forceinline__ uint16_t f2bf(float f) {
    union { float f; uint32_t i; } x; x.f = f;
    return (uint16_t)((x.i + 0x7fffu + ((x.i >> 16) & 1u)) >> 16);
}
__device__ __forceinline__ uint32_t fbits(float f) {
    union { float f; uint32_t i; } x; x.f = f; return x.i;
}

__global__ __launch_bounds__(256, 3)
void lepe_attn(const float* __restrict__ qkv,
               const float* __restrict__ conv_w,
               const float* __restrict__ conv_b,
               float* __restrict__ out)
{
    __shared__ uint16_t k_lds[256 * KSTR];       // 20480 B
    __shared__ uint16_t vt_lds[32 * VSTR];       // 16896 B
    __shared__ float w_lds[288];                 //  1152 B
    __shared__ float b_lds[32];                  //   128 B  => total 38656 B

    const int tid  = threadIdx.x;
    const int lane = tid & 63;
    const int wave = tid >> 6;
    const int l15  = lane & 15;
    const int quad = lane >> 4;

    const int blk  = blockIdx.x;
    const int head = blk & 7;
    const int wid  = blk >> 3;
    const int b    = wid >> 7;
    const int rem  = wid & 127;
    const int dpt  = rem >> 2;
    const int nw   = rem & 3;

    const long base_l = (long)dpt * 1024 + nw * 8;
    const int  hc     = head * 32;

    const float c1 = 0.17677669529663687f * 1.4426950408889634f; // SCALE * log2(e)

    // ---- Q prefetch: all 4 iterations, issued BEFORE staging loads ----
    float4 qpre[8];
    #pragma unroll
    for (int it = 0; it < 4; ++it) {
        const int  sq = (wave * 4 + it) * 16 + l15;
        const long ql = base_l + (sq >> 3) * 32 + (sq & 7);
        const float* qp = qkv + (((long)b * 32768 + ql) * 256 + hc + quad * 8);
        qpre[it * 2]     = ((const float4*)qp)[0];
        qpre[it * 2 + 1] = ((const float4*)qp)[1];
    }

    // ---- stage K [t][hd] bf16 (pad-40), V^T [hd][t] bf16, LePE weights fp32 ----
    {
        const int  s = tid;
        const long l = base_l + (s >> 3) * 32 + (s & 7);
        const float* kp = qkv + (((long)(2 + b) * 32768 + l) * 256 + hc);
        const float* vp = qkv + (((long)(4 + b) * 32768 + l) * 256 + hc);
        #pragma unroll
        for (int j = 0; j < 8; ++j) {
            float4 kv = ((const float4*)kp)[j];
            u16x4 kb = { f2bf(kv.x), f2bf(kv.y), f2bf(kv.z), f2bf(kv.w) };
            *(u16x4*)&k_lds[s * KSTR + j * 4] = kb;
            float4 vv = ((const float4*)vp)[j];
            vt_lds[(j * 4 + 0) * VSTR + s] = f2bf(vv.x);
            vt_lds[(j * 4 + 1) * VSTR + s] = f2bf(vv.y);
            vt_lds[(j * 4 + 2) * VSTR + s] = f2bf(vv.z);
            vt_lds[(j * 4 + 3) * VSTR + s] = f2bf(vv.w);
        }
        for (int i = tid; i < 288; i += 256) w_lds[i] = conv_w[head * 288 + i];
        if (tid < 32) b_lds[tid] = conv_b[hc + tid];
    }

    // convert Q to MFMA B-fragments while staging stores drain (pre-scaled by SCALE*log2e)
    bf16x8 qfa[4];
    #pragma unroll
    for (int it = 0; it < 4; ++it) {
        float4 q0 = qpre[it * 2], q1 = qpre[it * 2 + 1];
        bf16x8 f;
        f[0] = (short)f2bf(q0.x * c1); f[1] = (short)f2bf(q0.y * c1);
        f[2] = (short)f2bf(q0.z * c1); f[3] = (short)f2bf(q0.w * c1);
        f[4] = (short)f2bf(q1.x * c1); f[5] = (short)f2bf(q1.y * c1);
        f[6] = (short)f2bf(q1.z * c1); f[7] = (short)f2bf(q1.w * c1);
        qfa[it] = f;
    }
    __syncthreads();

    // hoist this lane's LePE weights (channels l15 and 16+l15)
    float wgt[18], bia[2];
    #pragma unroll
    for (int n = 0; n < 2; ++n) {
        #pragma unroll
        for (int i = 0; i < 9; ++i) wgt[n * 9 + i] = w_lds[(n * 16 + l15) * 9 + i];
        bia[n] = b_lds[n * 16 + l15];
    }

    const f32x4 zero4 = {0.f, 0.f, 0.f, 0.f};

    #pragma unroll
    for (int it = 0; it < 4; ++it) {
        const int rt = wave * 4 + it;

        // ---- S^T = K Q^T: lane holds S^T[key=16t+quad*4+r][query=rt*16+l15] ----
        f32x4 accS[16];
        __builtin_amdgcn_s_setprio(1);
        #pragma unroll
        for (int t = 0; t < 16; ++t) {
            bf16x8 afrag = *(const bf16x8*)&k_lds[(t * 16 + l15) * KSTR + quad * 8];
            accS[t] = __builtin_amdgcn_mfma_f32_16x16x32_bf16(afrag, qfa[it], zero4, 0, 0, 0);
        }
        __builtin_amdgcn_s_setprio(0);

        // ---- LePE (independent of accS): fills S^T MFMA drain latency ----
        const int hrow = rt * 2 + (quad >> 1);
        const int wsel = quad & 1;
        float lep[2][4];
        #pragma unroll
        for (int n = 0; n < 2; ++n) {
            const int d = n * 16 + l15;
            float lep0 = bia[n], lep1 = bia[n], lep2 = bia[n], lep3 = bia[n];
            #pragma unroll
            for (int dy = 0; dy < 3; ++dy) {
                const int hh = hrow + dy - 1;
                float e0 = 0.f, e1 = 0.f, e2 = 0.f, e3 = 0.f, e4 = 0.f, e5 = 0.f;
                if (hh >= 0 && hh < 32) {
                    uint4 rv = *(const uint4*)&vt_lds[d * VSTR + hh * 8];
                    float c0 = bf2f_lo(rv.x), c1v = bf2f_hi(rv.x);
                    float c2 = bf2f_lo(rv.y), c3 = bf2f_hi(rv.y);
                    float c4 = bf2f_lo(rv.z), c5 = bf2f_hi(rv.z);
                    float c6 = bf2f_lo(rv.w), c7 = bf2f_hi(rv.w);
                    e0 = wsel ? c3 : 0.f;  e1 = wsel ? c4 : c0;
                    e2 = wsel ? c5 : c1v;  e3 = wsel ? c6 : c2;
                    e4 = wsel ? c7 : c3;   e5 = wsel ? 0.f : c4;
                }
                const float w0 = wgt[n * 9 + dy * 3 + 0];
                const float w1 = wgt[n * 9 + dy * 3 + 1];
                const float w2 = wgt[n * 9 + dy * 3 + 2];
                lep0 = fmaf(w0, e0, fmaf(w1, e1, fmaf(w2, e2, lep0)));
                lep1 = fmaf(w0, e1, fmaf(w1, e2, fmaf(w2, e3, lep1)));
                lep2 = fmaf(w0, e2, fmaf(w1, e3, fmaf(w2, e4, lep2)));
                lep3 = fmaf(w0, e3, fmaf(w1, e4, fmaf(w2, e5, lep3)));
            }
            lep[n][0] = lep0; lep[n][1] = lep1; lep[n][2] = lep2; lep[n][3] = lep3;
        }

        // ---- softmax (max-free) + pack P to bf16 pairs; accS[t] dies into pkl/pkh[t] ----
        uint32_t pkl[16], pkh[16];
        float ssum = 0.f;
        #pragma unroll
        for (int t = 0; t < 16; ++t) {
            float p0 = exp2f(accS[t][0]);
            float p1 = exp2f(accS[t][1]);
            float p2 = exp2f(accS[t][2]);
            float p3 = exp2f(accS[t][3]);
            ssum += (p0 + p1) + (p2 + p3);
            pkl[t] = ((fbits(p0) + 0x8000u) >> 16) | ((fbits(p1) + 0x8000u) & 0xffff0000u);
            pkh[t] = ((fbits(p2) + 0x8000u) >> 16) | ((fbits(p3) + 0x8000u) & 0xffff0000u);
        }
        ssum += __shfl_xor(ssum, 16);
        ssum += __shfl_xor(ssum, 32);
        const float linv = __builtin_amdgcn_rcpf(ssum);
        // output row r of this lane is query quad*4+r; its sum lives at lane l15'=quad*4+r
        float linv4[4];
        #pragma unroll
        for (int r = 0; r < 4; ++r) linv4[r] = __shfl(linv, quad * 4 + r);

        // ---- PV: in-register quad exchange (replaces p_lds roundtrip) ----
        // Lane (l15,q) holds keys {16t+4q+r}; A-fragment needs keys {32cc+8q+0..7}.
        // permlane32_swap then permlane16_swap on (tile 2cc, tile 2cc+1) pairs yields
        // frag dwords: d0=lo(qs=2(q&1)), d1=hi(qs), d2=lo(qs+1), d3=hi(qs+1).
        f32x4 accO[2] = {zero4, zero4};
        __builtin_amdgcn_s_setprio(1);
        #pragma unroll
        for (int cc = 0; cc < 8; ++cc) {
            uint32_t a0 = pkl[2 * cc], a1 = pkl[2 * cc + 1];
            uint32_t b0 = pkh[2 * cc], b1 = pkh[2 * cc + 1];
            asm("v_permlane32_swap_b32 %0, %1" : "+v"(a0), "+v"(a1));
            asm("v_permlane32_swap_b32 %0, %1" : "+v"(b0), "+v"(b1));
            asm("v_permlane16_swap_b32 %0, %1" : "+v"(a0), "+v"(a1));
            asm("v_permlane16_swap_b32 %0, %1" : "+v"(b0), "+v"(b1));
            u32x4 pv = {a0, b0, a1, b1};
            bf16x8 pa = __builtin_bit_cast(bf16x8, pv);
            const int kb = cc * 32 + quad * 8;
            bf16x8 vb0 = *(const bf16x8*)&vt_lds[l15 * VSTR + kb];
            accO[0] = __builtin_amdgcn_mfma_f32_16x16x32_bf16(pa, vb0, accO[0], 0, 0, 0);
            bf16x8 vb1 = *(const bf16x8*)&vt_lds[(16 + l15) * VSTR + kb];
            accO[1] = __builtin_amdgcn_mfma_f32_16x16x32_bf16(pa, vb1, accO[1], 0, 0, 0);
        }
        __builtin_amdgcn_s_setprio(0);

        // ---- epilogue: normalize, add LePE, store ----
        #pragma unroll
        for (int n = 0; n < 2; ++n) {
            const int d = n * 16 + l15;
            #pragma unroll
            for (int r = 0; r < 4; ++r) {
                const int s  = rt * 16 + quad * 4 + r;
                const int h  = s >> 3, w_ = s & 7;
                const long ol = base_l + h * 32 + w_;
                out[((long)b * 32768 + ol) * 256 + hc + d] = accO[n][r] * linv4[r] + lep[n][r];
            }
        }
    }
}

extern "C" void kernel_launch(void* const* d_in, const int* in_sizes, int n_in,
                              void* d_out, int out_size, void* d_ws, size_t ws_size,
                              hipStream_t stream)
{
    const float* qkv = (const float*)d_in[0];
    const float* cw  = (const float*)d_in[1];
    const float* cb  = (const float*)d_in[2];
    float* o = (float*)d_out;
    lepe_attn<<<2048, 256, 0, stream>>>(qkv, cw, cb, o);
}